// Round 11
// baseline (483.661 us; speedup 1.0000x reference)
//
#include <hip/hip_runtime.h>
#include <hip/hip_bf16.h>

typedef __hip_bfloat16 bf16;
typedef short bf16x8 __attribute__((ext_vector_type(8)));
typedef float f32x4 __attribute__((ext_vector_type(4)));
typedef float f32x16 __attribute__((ext_vector_type(16)));

__device__ __forceinline__ float b2f(bf16 v) { return __bfloat162float(v); }
__device__ __forceinline__ void storev(float* p, float v) { *p = v; }
__device__ __forceinline__ void storev(bf16* p, float v) { *p = __float2bfloat16(v); }

__device__ __forceinline__ void store4(float* p, float a, float b, float c, float d) {
  *(float4*)p = make_float4(a, b, c, d);
}
__device__ __forceinline__ void store4(bf16* p, float a, float b, float c, float d) {
  bf16 pk[4] = {__float2bfloat16(a), __float2bfloat16(b), __float2bfloat16(c),
                __float2bfloat16(d)};
  *(uint2*)p = *(uint2*)pk;
}

// async global->LDS, 16B per lane. LDS dest must be wave base + lane*16.
__device__ __forceinline__ void gl2lds16(const bf16* g, bf16* l) {
  __builtin_amdgcn_global_load_lds(
      (const __attribute__((address_space(1))) unsigned int*)g,
      (__attribute__((address_space(3))) unsigned int*)l, 16, 0, 0);
}
__device__ __forceinline__ void gl2lds16f(const float* g, float* l) {
  __builtin_amdgcn_global_load_lds(
      (const __attribute__((address_space(1))) unsigned int*)g,
      (__attribute__((address_space(3))) unsigned int*)l, 16, 0, 0);
}

// ---------------------------------------------------------------------------
// Fused prologue (proven): weight transpose (4 layers via blockIdx.y) +
// conv_w convert + im2col + x zero-fill (for the embed atomic K-split)
// in ONE dispatch. bid<864: transpose; 864..959: convert; 960..1215: im2col;
// 1216..1407: zero x (768 block-equivs x 4 KB = 3 MB).
// ---------------------------------------------------------------------------
__global__ __launch_bounds__(256) void prologue_all(
    const float* __restrict__ wqkv, const float* __restrict__ wo,
    const float* __restrict__ w1, const float* __restrict__ w2,
    bf16* __restrict__ tqkv, bf16* __restrict__ two,
    bf16* __restrict__ t1, bf16* __restrict__ t2,
    const float* __restrict__ convw, bf16* __restrict__ cwb,
    const float* __restrict__ vol, bf16* __restrict__ patchA,
    float* __restrict__ xz) {
  int bid = blockIdx.x;
  size_t L = blockIdx.y;
  int tid = threadIdx.x;

  if (bid >= 864) {
    if (bid < 960) {
      int cid = (bid - 864) * 4 + (int)L;
      int i = (cid * 256 + tid) * 4;
      float4 v = *(const float4*)&convw[i];
      bf16 pk[4] = {__float2bfloat16(v.x), __float2bfloat16(v.y),
                    __float2bfloat16(v.z), __float2bfloat16(v.w)};
      *(uint2*)&cwb[i] = *(uint2*)pk;
    } else if (bid < 1216) {
      int t = (bid - 960) * 4 + (int)L;
      int b = t >> 9, n = t & 511;
      int pd = n >> 6, ph = (n >> 3) & 7, pw = n & 7;
      const float* vb = vol + ((size_t)b << 18);
      for (int l = tid; l < 512; l += 256) {
        int i = l >> 6, j = (l >> 3) & 7, k = l & 7;
        patchA[(size_t)t * 512 + l] =
            __float2bfloat16(vb[(pd * 8 + i) * 4096 + (ph * 8 + j) * 64 + (pw * 8 + k)]);
      }
    } else {
      // zero x: cid in [0,768), 4 KB each (256 thr x 16 B)
      int cid = (bid - 1216) * 4 + (int)L;
      *(float4*)&xz[(size_t)cid * 1024 + tid * 4] = make_float4(0.f, 0.f, 0.f, 0.f);
    }
    return;
  }

  const float* in;
  bf16* out;
  int R, C, tc, t0;
  if (bid < 216)       { in = wqkv + L * 768 * 2304; out = tqkv + L * 768 * 2304; R = 768;  C = 2304; tc = 36; t0 = bid; }
  else if (bid < 288)  { in = wo + L * 768 * 768;    out = two + L * 768 * 768;   R = 768;  C = 768;  tc = 12; t0 = bid - 216; }
  else if (bid < 576)  { in = w1 + L * 768 * 3072;   out = t1 + L * 768 * 3072;   R = 768;  C = 3072; tc = 48; t0 = bid - 288; }
  else                 { in = w2 + L * 3072 * 768;   out = t2 + L * 3072 * 768;   R = 3072; C = 768;  tc = 12; t0 = bid - 576; }
  int r0 = (t0 / tc) * 128, c0 = (t0 % tc) * 64;
  __shared__ float tile[8192];
  // Stage: LDS dest linear (s*16 B); global source 16B-granule XOR-swizzled.
#pragma unroll
  for (int it = 0; it < 8; ++it) {
    int s = tid + it * 256;
    int r = s >> 4, cc = s & 15;
    int csrc = (cc ^ ((r >> 3) & 7)) << 2;
    gl2lds16f(&in[(size_t)(r0 + r) * C + c0 + csrc], &tile[s * 4]);
  }
  __syncthreads();
#pragma unroll
  for (int it = 0; it < 4; ++it) {
    int idx = tid + it * 256;
    int c = idx >> 4, rb = (idx & 15) * 8;
    int slot = (c >> 2) ^ ((rb >> 3) & 7);
    int base = rb * 64 + slot * 4 + (c & 3);
    bf16 pk[8];
#pragma unroll
    for (int e = 0; e < 8; ++e) pk[e] = __float2bfloat16(tile[base + e * 64]);
    *(uint4*)&out[(size_t)(c0 + c) * R + r0 + rb] = *(uint4*)pk;
  }
}

// ---------------------------------------------------------------------------
// LayerNorm over last dim (768), fp32 in, OutT out. One row per wave,
// 4 rows/block, grid 256. Single global pass, shfl reduce, vector stores.
// ---------------------------------------------------------------------------
template <typename OutT>
__global__ __launch_bounds__(256) void ln_kernel(const float* __restrict__ x,
                                                 const float* __restrict__ w,
                                                 const float* __restrict__ b,
                                                 OutT* __restrict__ out) {
  int row = (blockIdx.x << 2) + (threadIdx.x >> 6);
  int lane = threadIdx.x & 63;
  const float* xr = x + (size_t)row * 768;
  float4 v[3];
  float s = 0.f, ss = 0.f;
#pragma unroll
  for (int j = 0; j < 3; ++j) {
    v[j] = *(const float4*)&xr[j * 256 + lane * 4];
    s += v[j].x + v[j].y + v[j].z + v[j].w;
    ss += v[j].x * v[j].x + v[j].y * v[j].y + v[j].z * v[j].z + v[j].w * v[j].w;
  }
#pragma unroll
  for (int off = 32; off; off >>= 1) {
    s += __shfl_xor(s, off);
    ss += __shfl_xor(ss, off);
  }
  float m = s * (1.f / 768.f);
  float r = rsqrtf(ss * (1.f / 768.f) - m * m + 1e-5f);
  OutT* orow = out + (size_t)row * 768;
#pragma unroll
  for (int j = 0; j < 3; ++j) {
    int cidx = j * 256 + lane * 4;
    float4 wv = *(const float4*)&w[cidx];
    float4 bv = *(const float4*)&b[cidx];
    store4(orow + cidx,
           (v[j].x - m) * r * wv.x + bv.x,
           (v[j].y - m) * r * wv.y + bv.y,
           (v[j].z - m) * r * wv.z + bv.z,
           (v[j].w - m) * r * wv.w + bv.w);
  }
}

// ---------------------------------------------------------------------------
// MFMA bf16 GEMM (B^T layout), global_load_lds staging, SK=64.
// 32x32x16 MFMA (proven round-10 form): one 32x32 output tile per wave,
// 2x2 wave grid, 2-barrier skeleton, T21 XOR-swizzle pair.
// EPI: 2 +bias,tanh->bf16 | 4 qkv split | 5 atomicAdd f32 (+bias z==0)
//      6 atomicAdd f32 (+bias+pos z==0; embed with pre-zeroed x)
// ---------------------------------------------------------------------------
template <int BM, int BN, int EPI>
__global__ __launch_bounds__(256) void mfma_gemm(
    const bf16* __restrict__ A, const bf16* __restrict__ Bt,
    const float* __restrict__ bias, const float* __restrict__ aux,
    bf16* __restrict__ vt,
    void* __restrict__ Cout, int M, int N, int K) {
  __shared__ bf16 As[BM * 64];
  __shared__ bf16 Bs[BN * 64];
  int tid = threadIdx.x;
  int wave = tid >> 6, lane = tid & 63;
  int wm = wave >> 1, wn = wave & 1;
  int l31 = lane & 31, half = lane >> 5;
  int m0 = blockIdx.y * BM, n0 = blockIdx.x * BN;
  int kspan = K / gridDim.z;
  int kbeg = blockIdx.z * kspan, kend = kbeg + kspan;

  f32x16 acc;
#pragma unroll
  for (int r = 0; r < 16; ++r) acc[r] = 0.f;

  int arow = wm * 32 + l31;
  int brow = wn * 32 + l31;
  int axor = arow & 7, bxor = brow & 7;

  for (int k0 = kbeg; k0 < kend; k0 += 64) {
    // stage A and B: lane DMAs 16B; LDS linear dest, source chunk XOR'd so
    // LDS[row][cc] = A[row][cc ^ (row&7)] (T21 involution).
#pragma unroll
    for (int it = 0; it < BM * 8 / 256; ++it) {
      int c = tid + it * 256;
      int row = c >> 3, cc = c & 7;
      gl2lds16(&A[(size_t)(m0 + row) * K + k0 + (cc ^ (row & 7)) * 8], &As[c * 8]);
    }
#pragma unroll
    for (int it = 0; it < BN * 8 / 256; ++it) {
      int c = tid + it * 256;
      int row = c >> 3, cc = c & 7;
      gl2lds16(&Bt[(size_t)(n0 + row) * K + k0 + (cc ^ (row & 7)) * 8], &Bs[c * 8]);
    }
    __syncthreads();
#pragma unroll
    for (int kk = 0; kk < 4; ++kk) {
      int j = kk * 2 + half;  // 16B k-chunk index 0..7
      bf16x8 af = *(const bf16x8*)&As[arow * 64 + (j ^ axor) * 8];
      bf16x8 bfr = *(const bf16x8*)&Bs[brow * 64 + (j ^ bxor) * 8];
      acc = __builtin_amdgcn_mfma_f32_32x32x16_bf16(af, bfr, acc, 0, 0, 0);
    }
    __syncthreads();
  }

  int col = n0 + wn * 32 + l31;
  int rbase = m0 + wm * 32 + 4 * half;
  if (EPI == 4) {
    if (col < 1536) {
#pragma unroll
      for (int r = 0; r < 16; ++r) {
        int row = rbase + (r & 3) + 8 * (r >> 2);
        ((bf16*)Cout)[(size_t)row * 1536 + col] = __float2bfloat16(acc[r]);
      }
    } else {
      int cl = col - 1536;
      int hh = cl >> 6, dd = cl & 63;
#pragma unroll
      for (int g = 0; g < 4; ++g) {
        int row0 = rbase + 8 * g;
        int bb = row0 >> 9, tok = row0 & 511;
        bf16 pk[4];
#pragma unroll
        for (int t = 0; t < 4; ++t) pk[t] = __float2bfloat16(acc[g * 4 + t]);
        *(uint2*)&vt[((size_t)(bb * 12 + hh) * 64 + dd) * 512 + tok] = *(uint2*)pk;
      }
    }
  } else if (EPI == 5 || EPI == 6) {
    float bv = (blockIdx.z == 0) ? bias[col] : 0.f;
#pragma unroll
    for (int r = 0; r < 16; ++r) {
      int row = rbase + (r & 3) + 8 * (r >> 2);
      float v = acc[r] + bv;
      if (EPI == 6 && blockIdx.z == 0) v += aux[(size_t)(row & 511) * N + col];
      unsafeAtomicAdd(&((float*)Cout)[(size_t)row * N + col], v);
    }
  } else {
    float bv = bias[col];
#pragma unroll
    for (int r = 0; r < 16; ++r) {
      int row = rbase + (r & 3) + 8 * (r >> 2);
      float v = acc[r] + bv;
      if (EPI == 2) v = tanhf(v);
      ((bf16*)Cout)[(size_t)row * N + col] = __float2bfloat16(v);
    }
  }
}

// ---------------------------------------------------------------------------
// MFMA attention (round-9 best form + T5 setprio around MFMA clusters).
// Block = (b*12+h, 32-query tile), 128 thr = 2 waves. Each round stages TWO
// 64x64 chunks (KVs 16 KB): 8 rounds, 16 barriers.
// ---------------------------------------------------------------------------
__global__ __launch_bounds__(128) void attn_mfma(const bf16* __restrict__ qk,
                                                 const bf16* __restrict__ Vt,
                                                 bf16* __restrict__ o) {
  constexpr int PS = 520;  // P stride: 1040 B, 16B-aligned, banks shift by 4
  __shared__ bf16 KVs[2][64 * 64];
  __shared__ bf16 P[32 * PS];
  int bh = blockIdx.x;
  int b = bh / 12, hh = bh % 12;
  int q0 = blockIdx.y * 32;
  int tid = threadIdx.x;
  int wave = tid >> 6, lane = tid & 63;
  int n15 = lane & 15, quad = lane >> 4;
  const bf16* qkb = qk + (size_t)b * 512 * 1536;
  int ql = wave * 16 + n15;

  const bf16* qp = qkb + (size_t)(q0 + ql) * 1536 + hh * 64 + quad * 8;
  bf16x8 qf0 = *(const bf16x8*)qp;
  bf16x8 qf1 = *(const bf16x8*)(qp + 32);

  f32x4 S[32];
#pragma unroll
  for (int i = 0; i < 32; ++i) S[i] = (f32x4){0.f, 0.f, 0.f, 0.f};

  const bf16* kbase = qkb + 768 + hh * 64;
#pragma unroll
  for (int kr = 0; kr < 4; ++kr) {
    __syncthreads();
#pragma unroll
    for (int h = 0; h < 2; ++h) {
      int kc = kr * 2 + h;
#pragma unroll
      for (int it = 0; it < 4; ++it) {
        int c = tid + it * 128;
        int r = c >> 3, cc = c & 7;
        gl2lds16(&kbase[(size_t)(kc * 64 + r) * 1536 + cc * 8], &KVs[h][c * 8]);
      }
    }
    __syncthreads();
    __builtin_amdgcn_s_setprio(1);
#pragma unroll
    for (int h = 0; h < 2; ++h) {
      int kc = kr * 2 + h;
#pragma unroll
      for (int t = 0; t < 4; ++t) {
        int idx = kc * 4 + t;
        bf16x8 a0 = *(const bf16x8*)&KVs[h][(t * 16 + n15) * 64 + quad * 8];
        bf16x8 a1 = *(const bf16x8*)&KVs[h][(t * 16 + n15) * 64 + 32 + quad * 8];
        S[idx] = __builtin_amdgcn_mfma_f32_16x16x32_bf16(a0, qf0, S[idx], 0, 0, 0);
        S[idx] = __builtin_amdgcn_mfma_f32_16x16x32_bf16(a1, qf1, S[idx], 0, 0, 0);
      }
    }
    __builtin_amdgcn_s_setprio(0);
  }

  float mx = -1e30f;
#pragma unroll
  for (int i = 0; i < 32; ++i)
#pragma unroll
    for (int r = 0; r < 4; ++r) { S[i][r] *= 0.125f; mx = fmaxf(mx, S[i][r]); }
  mx = fmaxf(mx, __shfl_xor(mx, 16));
  mx = fmaxf(mx, __shfl_xor(mx, 32));
  float sum = 0.f;
#pragma unroll
  for (int i = 0; i < 32; ++i)
#pragma unroll
    for (int r = 0; r < 4; ++r) { float e = __expf(S[i][r] - mx); S[i][r] = e; sum += e; }
  sum += __shfl_xor(sum, 16);
  sum += __shfl_xor(sum, 32);
  float inv = 1.f / sum;

#pragma unroll
  for (int i = 0; i < 32; ++i) {
    bf16 pk[4];
#pragma unroll
    for (int r = 0; r < 4; ++r) pk[r] = __float2bfloat16(S[i][r] * inv);
    *(uint2*)&P[(size_t)ql * PS + i * 16 + quad * 4] = *(uint2*)pk;
  }

  f32x4 oacc[4];
#pragma unroll
  for (int dt = 0; dt < 4; ++dt) oacc[dt] = (f32x4){0.f, 0.f, 0.f, 0.f};
  const bf16* vtb = Vt + (size_t)bh * 64 * 512;
#pragma unroll
  for (int kr = 0; kr < 4; ++kr) {
    __syncthreads();
#pragma unroll
    for (int h = 0; h < 2; ++h) {
      int kv = kr * 2 + h;
#pragma unroll
      for (int it = 0; it < 4; ++it) {
        int c = tid + it * 128;
        int r = c >> 3, cc = c & 7;
        gl2lds16(&vtb[(size_t)r * 512 + kv * 64 + cc * 8], &KVs[h][c * 8]);
      }
    }
    __syncthreads();
    __builtin_amdgcn_s_setprio(1);
#pragma unroll
    for (int h = 0; h < 2; ++h) {
      int kv = kr * 2 + h;
      bf16x8 p0 = *(const bf16x8*)&P[(size_t)ql * PS + kv * 64 + quad * 8];
      bf16x8 p1 = *(const bf16x8*)&P[(size_t)ql * PS + kv * 64 + 32 + quad * 8];
#pragma unroll
      for (int dt = 0; dt < 4; ++dt) {
        bf16x8 v0 = *(const bf16x8*)&KVs[h][(dt * 16 + n15) * 64 + quad * 8];
        bf16x8 v1 = *(const bf16x8*)&KVs[h][(dt * 16 + n15) * 64 + 32 + quad * 8];
        oacc[dt] = __builtin_amdgcn_mfma_f32_16x16x32_bf16(p0, v0, oacc[dt], 0, 0, 0);
        oacc[dt] = __builtin_amdgcn_mfma_f32_16x16x32_bf16(p1, v1, oacc[dt], 0, 0, 0);
      }
    }
    __builtin_amdgcn_s_setprio(0);
  }

#pragma unroll
  for (int dt = 0; dt < 4; ++dt)
#pragma unroll
    for (int r = 0; r < 4; ++r) {
      int tok = q0 + wave * 16 + quad * 4 + r;
      o[((size_t)b * 512 + tok) * 768 + hh * 64 + dt * 16 + n15] =
          __float2bfloat16(oacc[dt][r]);
    }
}

// ---------------------------------------------------------------------------
extern "C" void kernel_launch(void* const* d_in, const int* in_sizes, int n_in,
                              void* d_out, int out_size, void* d_ws, size_t ws_size,
                              hipStream_t stream) {
  const float* volume = (const float*)d_in[0];
  const float* conv_w = (const float*)d_in[1];
  const float* conv_b = (const float*)d_in[2];
  const float* pos    = (const float*)d_in[3];
  const float* ln1w   = (const float*)d_in[4];
  const float* ln1b   = (const float*)d_in[5];
  const float* wqkv   = (const float*)d_in[6];
  const float* wo     = (const float*)d_in[7];
  const float* bo     = (const float*)d_in[8];
  const float* ln2w   = (const float*)d_in[9];
  const float* ln2b   = (const float*)d_in[10];
  const float* w1     = (const float*)d_in[11];
  const float* b1     = (const float*)d_in[12];
  const float* w2     = (const float*)d_in[13];
  const float* b2     = (const float*)d_in[14];
  const float* lnfw   = (const float*)d_in[15];
  const float* lnfb   = (const float*)d_in[16];

  // ws layout (~73 MB of ~268 MB)
  char* w = (char*)d_ws;
  float* x    = (float*)(w + 0);           // fp32 residual [1024][768]
  bf16* h     = (bf16*)(w + 3145728);      // ln out [1024][768]
  bf16* qk    = (bf16*)(w + 4718592);      // Q|K [1024][1536]; aliases patchA
  bf16* patchA= qk;                        // im2col [1024][512]
  bf16* Vt    = (bf16*)(w + 7864320);      // V^T [24][64][512]
  bf16* oact  = (bf16*)(w + 9437184);      // attn-o / mlp act [1024][3072]
  bf16* cwb   = (bf16*)(w + 15728640);     // conv_w bf16 [768][512]
  bf16* tqkv  = (bf16*)(w + 16515072);     // 4 x [2304][768]
  bf16* two   = (bf16*)(w + 30670848);     // 4 x [768][768]
  bf16* t1    = (bf16*)(w + 35389440);     // 4 x [3072][768]
  bf16* t2    = (bf16*)(w + 54263808);     // 4 x [768][3072]

  prologue_all<<<dim3(1408, 4), 256, 0, stream>>>(
      wqkv, wo, w1, w2, tqkv, two, t1, t2, conv_w, cwb, volume, patchA, x);
  mfma_gemm<64, 64, 6><<<dim3(12, 16, 2), 256, 0, stream>>>(
      patchA, cwb, conv_b, pos, nullptr, x, 1024, 768, 512);

  for (int L = 0; L < 4; ++L) {
    ln_kernel<bf16><<<256, 256, 0, stream>>>(x, ln1w + L * 768, ln1b + L * 768, h);
    mfma_gemm<64, 64, 4><<<dim3(36, 16), 256, 0, stream>>>(
        h, tqkv + (size_t)L * 768 * 2304, nullptr, nullptr, Vt, qk, 1024, 2304, 768);
    attn_mfma<<<dim3(24, 16), 128, 0, stream>>>(qk, Vt, oact);
    mfma_gemm<64, 64, 5><<<dim3(12, 16, 4), 256, 0, stream>>>(
        oact, two + (size_t)L * 768 * 768, bo + L * 768, nullptr, nullptr, x, 1024, 768, 768);
    ln_kernel<bf16><<<256, 256, 0, stream>>>(x, ln2w + L * 768, ln2b + L * 768, h);
    mfma_gemm<64, 64, 2><<<dim3(48, 16), 256, 0, stream>>>(
        h, t1 + (size_t)L * 768 * 3072, b1 + L * 3072, nullptr, nullptr, oact, 1024, 3072, 768);
    mfma_gemm<64, 64, 5><<<dim3(12, 16, 4), 256, 0, stream>>>(
        oact, t2 + (size_t)L * 768 * 3072, b2 + L * 768, nullptr, nullptr, x, 1024, 768, 3072);
  }

  ln_kernel<float><<<256, 256, 0, stream>>>(x, lnfw, lnfb, (float*)d_out);
}

// Round 12
// 468.642 us; speedup vs baseline: 1.0320x; 1.0320x over previous
//
#include <hip/hip_runtime.h>
#include <hip/hip_bf16.h>

typedef __hip_bfloat16 bf16;
typedef short bf16x8 __attribute__((ext_vector_type(8)));
typedef float f32x4 __attribute__((ext_vector_type(4)));
typedef float f32x16 __attribute__((ext_vector_type(16)));

__device__ __forceinline__ float b2f(bf16 v) { return __bfloat162float(v); }
__device__ __forceinline__ void storev(float* p, float v) { *p = v; }
__device__ __forceinline__ void storev(bf16* p, float v) { *p = __float2bfloat16(v); }

__device__ __forceinline__ void store4(float* p, float a, float b, float c, float d) {
  *(float4*)p = make_float4(a, b, c, d);
}
__device__ __forceinline__ void store4(bf16* p, float a, float b, float c, float d) {
  bf16 pk[4] = {__float2bfloat16(a), __float2bfloat16(b), __float2bfloat16(c),
                __float2bfloat16(d)};
  *(uint2*)p = *(uint2*)pk;
}

// async global->LDS, 16B per lane. LDS dest must be wave base + lane*16.
__device__ __forceinline__ void gl2lds16(const bf16* g, bf16* l) {
  __builtin_amdgcn_global_load_lds(
      (const __attribute__((address_space(1))) unsigned int*)g,
      (__attribute__((address_space(3))) unsigned int*)l, 16, 0, 0);
}
__device__ __forceinline__ void gl2lds16f(const float* g, float* l) {
  __builtin_amdgcn_global_load_lds(
      (const __attribute__((address_space(1))) unsigned int*)g,
      (__attribute__((address_space(3))) unsigned int*)l, 16, 0, 0);
}

// ---------------------------------------------------------------------------
// Fused prologue (proven): weight transpose (4 layers via blockIdx.y) +
// conv_w convert + im2col in ONE dispatch.
// ---------------------------------------------------------------------------
__global__ __launch_bounds__(256) void prologue_all(
    const float* __restrict__ wqkv, const float* __restrict__ wo,
    const float* __restrict__ w1, const float* __restrict__ w2,
    bf16* __restrict__ tqkv, bf16* __restrict__ two,
    bf16* __restrict__ t1, bf16* __restrict__ t2,
    const float* __restrict__ convw, bf16* __restrict__ cwb,
    const float* __restrict__ vol, bf16* __restrict__ patchA) {
  int bid = blockIdx.x;
  size_t L = blockIdx.y;
  int tid = threadIdx.x;

  if (bid >= 864) {
    if (bid < 960) {
      int cid = (bid - 864) * 4 + (int)L;
      int i = (cid * 256 + tid) * 4;
      float4 v = *(const float4*)&convw[i];
      bf16 pk[4] = {__float2bfloat16(v.x), __float2bfloat16(v.y),
                    __float2bfloat16(v.z), __float2bfloat16(v.w)};
      *(uint2*)&cwb[i] = *(uint2*)pk;
    } else {
      int t = (bid - 960) * 4 + (int)L;
      int b = t >> 9, n = t & 511;
      int pd = n >> 6, ph = (n >> 3) & 7, pw = n & 7;
      const float* vb = vol + ((size_t)b << 18);
      for (int l = tid; l < 512; l += 256) {
        int i = l >> 6, j = (l >> 3) & 7, k = l & 7;
        patchA[(size_t)t * 512 + l] =
            __float2bfloat16(vb[(pd * 8 + i) * 4096 + (ph * 8 + j) * 64 + (pw * 8 + k)]);
      }
    }
    return;
  }

  const float* in;
  bf16* out;
  int R, C, tc, t0;
  if (bid < 216)       { in = wqkv + L * 768 * 2304; out = tqkv + L * 768 * 2304; R = 768;  C = 2304; tc = 36; t0 = bid; }
  else if (bid < 288)  { in = wo + L * 768 * 768;    out = two + L * 768 * 768;   R = 768;  C = 768;  tc = 12; t0 = bid - 216; }
  else if (bid < 576)  { in = w1 + L * 768 * 3072;   out = t1 + L * 768 * 3072;   R = 768;  C = 3072; tc = 48; t0 = bid - 288; }
  else                 { in = w2 + L * 3072 * 768;   out = t2 + L * 3072 * 768;   R = 3072; C = 768;  tc = 12; t0 = bid - 576; }
  int r0 = (t0 / tc) * 128, c0 = (t0 % tc) * 64;
  __shared__ float tile[8192];
  // Stage: LDS dest linear (s*16 B); global source 16B-granule XOR-swizzled.
#pragma unroll
  for (int it = 0; it < 8; ++it) {
    int s = tid + it * 256;
    int r = s >> 4, cc = s & 15;
    int csrc = (cc ^ ((r >> 3) & 7)) << 2;
    gl2lds16f(&in[(size_t)(r0 + r) * C + c0 + csrc], &tile[s * 4]);
  }
  __syncthreads();
#pragma unroll
  for (int it = 0; it < 4; ++it) {
    int idx = tid + it * 256;
    int c = idx >> 4, rb = (idx & 15) * 8;
    int slot = (c >> 2) ^ ((rb >> 3) & 7);
    int base = rb * 64 + slot * 4 + (c & 3);
    bf16 pk[8];
#pragma unroll
    for (int e = 0; e < 8; ++e) pk[e] = __float2bfloat16(tile[base + e * 64]);
    *(uint4*)&out[(size_t)(c0 + c) * R + r0 + rb] = *(uint4*)pk;
  }
}

// ---------------------------------------------------------------------------
// LayerNorm over last dim (768), fp32 in, OutT out. One row per wave,
// 4 rows/block, grid 256. Single global pass, shfl reduce, vector stores.
// ---------------------------------------------------------------------------
template <typename OutT>
__global__ __launch_bounds__(256) void ln_kernel(const float* __restrict__ x,
                                                 const float* __restrict__ w,
                                                 const float* __restrict__ b,
                                                 OutT* __restrict__ out) {
  int row = (blockIdx.x << 2) + (threadIdx.x >> 6);
  int lane = threadIdx.x & 63;
  const float* xr = x + (size_t)row * 768;
  float4 v[3];
  float s = 0.f, ss = 0.f;
#pragma unroll
  for (int j = 0; j < 3; ++j) {
    v[j] = *(const float4*)&xr[j * 256 + lane * 4];
    s += v[j].x + v[j].y + v[j].z + v[j].w;
    ss += v[j].x * v[j].x + v[j].y * v[j].y + v[j].z * v[j].z + v[j].w * v[j].w;
  }
#pragma unroll
  for (int off = 32; off; off >>= 1) {
    s += __shfl_xor(s, off);
    ss += __shfl_xor(ss, off);
  }
  float m = s * (1.f / 768.f);
  float r = rsqrtf(ss * (1.f / 768.f) - m * m + 1e-5f);
  OutT* orow = out + (size_t)row * 768;
#pragma unroll
  for (int j = 0; j < 3; ++j) {
    int cidx = j * 256 + lane * 4;
    float4 wv = *(const float4*)&w[cidx];
    float4 bv = *(const float4*)&b[cidx];
    store4(orow + cidx,
           (v[j].x - m) * r * wv.x + bv.x,
           (v[j].y - m) * r * wv.y + bv.y,
           (v[j].z - m) * r * wv.z + bv.z,
           (v[j].w - m) * r * wv.w + bv.w);
  }
}

// ---------------------------------------------------------------------------
// MFMA bf16 GEMM (B^T layout), global_load_lds staging, SK=64.
// v7 (round-10 proven): 32x32x16 MFMA, one 32x32 output tile per wave,
// 2x2 wave grid, 2-barrier skeleton, T21 XOR-swizzle pair (source chunk
// cc^(row&7) in DMA + same XOR on ds_read).
// Fragment maps: A/B lane l = [row=l&31][k=(l>>5)*8+e];
// C/D col=lane&31, row=(reg&3)+8*(reg>>2)+4*(lane>>5)  [m74/m101].
// EPI: 0 plain->bf16 | 2 +bias,tanh->bf16 | 3 +bias+pos->f32
//      4 qkv split | 5 atomicAdd into f32 C (+bias when z==0)
// ---------------------------------------------------------------------------
template <int BM, int BN, int EPI>
__global__ __launch_bounds__(256) void mfma_gemm(
    const bf16* __restrict__ A, const bf16* __restrict__ Bt,
    const float* __restrict__ bias, const float* __restrict__ aux,
    bf16* __restrict__ vt,
    void* __restrict__ Cout, int M, int N, int K) {
  __shared__ bf16 As[BM * 64];
  __shared__ bf16 Bs[BN * 64];
  int tid = threadIdx.x;
  int wave = tid >> 6, lane = tid & 63;
  int wm = wave >> 1, wn = wave & 1;
  int l31 = lane & 31, half = lane >> 5;
  int m0 = blockIdx.y * BM, n0 = blockIdx.x * BN;
  int kspan = K / gridDim.z;
  int kbeg = blockIdx.z * kspan, kend = kbeg + kspan;

  f32x16 acc;
#pragma unroll
  for (int r = 0; r < 16; ++r) acc[r] = 0.f;

  int arow = wm * 32 + l31;
  int brow = wn * 32 + l31;
  int axor = arow & 7, bxor = brow & 7;

  for (int k0 = kbeg; k0 < kend; k0 += 64) {
    // stage A and B: lane DMAs 16B; LDS linear dest, source chunk XOR'd so
    // LDS[row][cc] = A[row][cc ^ (row&7)] (T21 involution).
#pragma unroll
    for (int it = 0; it < BM * 8 / 256; ++it) {
      int c = tid + it * 256;
      int row = c >> 3, cc = c & 7;
      gl2lds16(&A[(size_t)(m0 + row) * K + k0 + (cc ^ (row & 7)) * 8], &As[c * 8]);
    }
#pragma unroll
    for (int it = 0; it < BN * 8 / 256; ++it) {
      int c = tid + it * 256;
      int row = c >> 3, cc = c & 7;
      gl2lds16(&Bt[(size_t)(n0 + row) * K + k0 + (cc ^ (row & 7)) * 8], &Bs[c * 8]);
    }
    __syncthreads();
#pragma unroll
    for (int kk = 0; kk < 4; ++kk) {
      int j = kk * 2 + half;  // 16B k-chunk index 0..7
      bf16x8 af = *(const bf16x8*)&As[arow * 64 + (j ^ axor) * 8];
      bf16x8 bfr = *(const bf16x8*)&Bs[brow * 64 + (j ^ bxor) * 8];
      acc = __builtin_amdgcn_mfma_f32_32x32x16_bf16(af, bfr, acc, 0, 0, 0);
    }
    __syncthreads();
  }

  int col = n0 + wn * 32 + l31;
  int rbase = m0 + wm * 32 + 4 * half;
  if (EPI == 4) {
    if (col < 1536) {
#pragma unroll
      for (int r = 0; r < 16; ++r) {
        int row = rbase + (r & 3) + 8 * (r >> 2);
        ((bf16*)Cout)[(size_t)row * 1536 + col] = __float2bfloat16(acc[r]);
      }
    } else {
      int cl = col - 1536;
      int hh = cl >> 6, dd = cl & 63;
#pragma unroll
      for (int g = 0; g < 4; ++g) {
        int row0 = rbase + 8 * g;
        int bb = row0 >> 9, tok = row0 & 511;
        bf16 pk[4];
#pragma unroll
        for (int t = 0; t < 4; ++t) pk[t] = __float2bfloat16(acc[g * 4 + t]);
        *(uint2*)&vt[((size_t)(bb * 12 + hh) * 64 + dd) * 512 + tok] = *(uint2*)pk;
      }
    }
  } else if (EPI == 5) {
    float bv = (blockIdx.z == 0) ? bias[col] : 0.f;
#pragma unroll
    for (int r = 0; r < 16; ++r) {
      int row = rbase + (r & 3) + 8 * (r >> 2);
      unsafeAtomicAdd(&((float*)Cout)[(size_t)row * N + col], acc[r] + bv);
    }
  } else {
    float bv = (EPI == 0) ? 0.f : bias[col];
#pragma unroll
    for (int r = 0; r < 16; ++r) {
      int row = rbase + (r & 3) + 8 * (r >> 2);
      float v = acc[r] + bv;
      if (EPI == 2) v = tanhf(v);
      if (EPI == 3) v += aux[(size_t)(row & 511) * N + col];
      if (EPI == 0 || EPI == 2)
        ((bf16*)Cout)[(size_t)row * N + col] = __float2bfloat16(v);
      else
        ((float*)Cout)[(size_t)row * N + col] = v;
    }
  }
}

// ---------------------------------------------------------------------------
// MFMA attention (round-9 best form). Block = (b*12+h, 32-query tile),
// 128 thr = 2 waves. Each round stages TWO 64x64 chunks (KVs 16 KB):
// 8 rounds, 16 barriers, drain amortized over 2x MFMA work.
// ---------------------------------------------------------------------------
__global__ __launch_bounds__(128) void attn_mfma(const bf16* __restrict__ qk,
                                                 const bf16* __restrict__ Vt,
                                                 bf16* __restrict__ o) {
  constexpr int PS = 520;  // P stride: 1040 B, 16B-aligned, banks shift by 4
  __shared__ bf16 KVs[2][64 * 64];
  __shared__ bf16 P[32 * PS];
  int bh = blockIdx.x;
  int b = bh / 12, hh = bh % 12;
  int q0 = blockIdx.y * 32;
  int tid = threadIdx.x;
  int wave = tid >> 6, lane = tid & 63;
  int n15 = lane & 15, quad = lane >> 4;
  const bf16* qkb = qk + (size_t)b * 512 * 1536;
  int ql = wave * 16 + n15;

  const bf16* qp = qkb + (size_t)(q0 + ql) * 1536 + hh * 64 + quad * 8;
  bf16x8 qf0 = *(const bf16x8*)qp;
  bf16x8 qf1 = *(const bf16x8*)(qp + 32);

  f32x4 S[32];
#pragma unroll
  for (int i = 0; i < 32; ++i) S[i] = (f32x4){0.f, 0.f, 0.f, 0.f};

  const bf16* kbase = qkb + 768 + hh * 64;
#pragma unroll
  for (int kr = 0; kr < 4; ++kr) {
    __syncthreads();
#pragma unroll
    for (int h = 0; h < 2; ++h) {
      int kc = kr * 2 + h;
#pragma unroll
      for (int it = 0; it < 4; ++it) {
        int c = tid + it * 128;
        int r = c >> 3, cc = c & 7;
        gl2lds16(&kbase[(size_t)(kc * 64 + r) * 1536 + cc * 8], &KVs[h][c * 8]);
      }
    }
    __syncthreads();
#pragma unroll
    for (int h = 0; h < 2; ++h) {
      int kc = kr * 2 + h;
#pragma unroll
      for (int t = 0; t < 4; ++t) {
        int idx = kc * 4 + t;
        bf16x8 a0 = *(const bf16x8*)&KVs[h][(t * 16 + n15) * 64 + quad * 8];
        bf16x8 a1 = *(const bf16x8*)&KVs[h][(t * 16 + n15) * 64 + 32 + quad * 8];
        S[idx] = __builtin_amdgcn_mfma_f32_16x16x32_bf16(a0, qf0, S[idx], 0, 0, 0);
        S[idx] = __builtin_amdgcn_mfma_f32_16x16x32_bf16(a1, qf1, S[idx], 0, 0, 0);
      }
    }
  }

  float mx = -1e30f;
#pragma unroll
  for (int i = 0; i < 32; ++i)
#pragma unroll
    for (int r = 0; r < 4; ++r) { S[i][r] *= 0.125f; mx = fmaxf(mx, S[i][r]); }
  mx = fmaxf(mx, __shfl_xor(mx, 16));
  mx = fmaxf(mx, __shfl_xor(mx, 32));
  float sum = 0.f;
#pragma unroll
  for (int i = 0; i < 32; ++i)
#pragma unroll
    for (int r = 0; r < 4; ++r) { float e = __expf(S[i][r] - mx); S[i][r] = e; sum += e; }
  sum += __shfl_xor(sum, 16);
  sum += __shfl_xor(sum, 32);
  float inv = 1.f / sum;

#pragma unroll
  for (int i = 0; i < 32; ++i) {
    bf16 pk[4];
#pragma unroll
    for (int r = 0; r < 4; ++r) pk[r] = __float2bfloat16(S[i][r] * inv);
    *(uint2*)&P[(size_t)ql * PS + i * 16 + quad * 4] = *(uint2*)pk;
  }

  f32x4 oacc[4];
#pragma unroll
  for (int dt = 0; dt < 4; ++dt) oacc[dt] = (f32x4){0.f, 0.f, 0.f, 0.f};
  const bf16* vtb = Vt + (size_t)bh * 64 * 512;
#pragma unroll
  for (int kr = 0; kr < 4; ++kr) {
    __syncthreads();
#pragma unroll
    for (int h = 0; h < 2; ++h) {
      int kv = kr * 2 + h;
#pragma unroll
      for (int it = 0; it < 4; ++it) {
        int c = tid + it * 128;
        int r = c >> 3, cc = c & 7;
        gl2lds16(&vtb[(size_t)r * 512 + kv * 64 + cc * 8], &KVs[h][c * 8]);
      }
    }
    __syncthreads();
#pragma unroll
    for (int h = 0; h < 2; ++h) {
      int kv = kr * 2 + h;
      bf16x8 p0 = *(const bf16x8*)&P[(size_t)ql * PS + kv * 64 + quad * 8];
      bf16x8 p1 = *(const bf16x8*)&P[(size_t)ql * PS + kv * 64 + 32 + quad * 8];
#pragma unroll
      for (int dt = 0; dt < 4; ++dt) {
        bf16x8 v0 = *(const bf16x8*)&KVs[h][(dt * 16 + n15) * 64 + quad * 8];
        bf16x8 v1 = *(const bf16x8*)&KVs[h][(dt * 16 + n15) * 64 + 32 + quad * 8];
        oacc[dt] = __builtin_amdgcn_mfma_f32_16x16x32_bf16(p0, v0, oacc[dt], 0, 0, 0);
        oacc[dt] = __builtin_amdgcn_mfma_f32_16x16x32_bf16(p1, v1, oacc[dt], 0, 0, 0);
      }
    }
  }

#pragma unroll
  for (int dt = 0; dt < 4; ++dt)
#pragma unroll
    for (int r = 0; r < 4; ++r) {
      int tok = q0 + wave * 16 + quad * 4 + r;
      o[((size_t)b * 512 + tok) * 768 + hh * 64 + dt * 16 + n15] =
          __float2bfloat16(oacc[dt][r]);
    }
}

// ---------------------------------------------------------------------------
extern "C" void kernel_launch(void* const* d_in, const int* in_sizes, int n_in,
                              void* d_out, int out_size, void* d_ws, size_t ws_size,
                              hipStream_t stream) {
  const float* volume = (const float*)d_in[0];
  const float* conv_w = (const float*)d_in[1];
  const float* conv_b = (const float*)d_in[2];
  const float* pos    = (const float*)d_in[3];
  const float* ln1w   = (const float*)d_in[4];
  const float* ln1b   = (const float*)d_in[5];
  const float* wqkv   = (const float*)d_in[6];
  const float* wo     = (const float*)d_in[7];
  const float* bo     = (const float*)d_in[8];
  const float* ln2w   = (const float*)d_in[9];
  const float* ln2b   = (const float*)d_in[10];
  const float* w1     = (const float*)d_in[11];
  const float* b1     = (const float*)d_in[12];
  const float* w2     = (const float*)d_in[13];
  const float* b2     = (const float*)d_in[14];
  const float* lnfw   = (const float*)d_in[15];
  const float* lnfb   = (const float*)d_in[16];

  // ws layout (~73 MB of ~268 MB)
  char* w = (char*)d_ws;
  float* x    = (float*)(w + 0);           // fp32 residual [1024][768]
  bf16* h     = (bf16*)(w + 3145728);      // ln out [1024][768]
  bf16* qk    = (bf16*)(w + 4718592);      // Q|K [1024][1536]; aliases patchA
  bf16* patchA= qk;                        // im2col [1024][512]
  bf16* Vt    = (bf16*)(w + 7864320);      // V^T [24][64][512]
  bf16* oact  = (bf16*)(w + 9437184);      // attn-o / mlp act [1024][3072]
  bf16* cwb   = (bf16*)(w + 15728640);     // conv_w bf16 [768][512]
  bf16* tqkv  = (bf16*)(w + 16515072);     // 4 x [2304][768]
  bf16* two   = (bf16*)(w + 30670848);     // 4 x [768][768]
  bf16* t1    = (bf16*)(w + 35389440);     // 4 x [3072][768]
  bf16* t2    = (bf16*)(w + 54263808);     // 4 x [768][3072]

  prologue_all<<<dim3(1216, 4), 256, 0, stream>>>(
      wqkv, wo, w1, w2, tqkv, two, t1, t2, conv_w, cwb, volume, patchA);
  mfma_gemm<64, 64, 3><<<dim3(12, 16), 256, 0, stream>>>(
      patchA, cwb, conv_b, pos, nullptr, x, 1024, 768, 512);

  for (int L = 0; L < 4; ++L) {
    ln_kernel<bf16><<<256, 256, 0, stream>>>(x, ln1w + L * 768, ln1b + L * 768, h);
    mfma_gemm<64, 64, 4><<<dim3(36, 16), 256, 0, stream>>>(
        h, tqkv + (size_t)L * 768 * 2304, nullptr, nullptr, Vt, qk, 1024, 2304, 768);
    attn_mfma<<<dim3(24, 16), 128, 0, stream>>>(qk, Vt, oact);
    mfma_gemm<64, 64, 5><<<dim3(12, 16, 2), 256, 0, stream>>>(
        oact, two + (size_t)L * 768 * 768, bo + L * 768, nullptr, nullptr, x, 1024, 768, 768);
    ln_kernel<bf16><<<256, 256, 0, stream>>>(x, ln2w + L * 768, ln2b + L * 768, h);
    mfma_gemm<64, 64, 2><<<dim3(48, 16), 256, 0, stream>>>(
        h, t1 + (size_t)L * 768 * 3072, b1 + L * 3072, nullptr, nullptr, oact, 1024, 3072, 768);
    mfma_gemm<64, 64, 5><<<dim3(12, 16, 4), 256, 0, stream>>>(
        oact, t2 + (size_t)L * 768 * 3072, b2 + L * 768, nullptr, nullptr, x, 1024, 768, 3072);
  }

  ln_kernel<float><<<256, 256, 0, stream>>>(x, lnfw, lnfb, (float*)d_out);
}